// Round 3
// baseline (3907.694 us; speedup 1.0000x reference)
//
#include <hip/hip_runtime.h>
#include <math.h>

#define H0 120
#define W0 120
#define H1 240
#define W1 240
#define L  14400   // 120*120
#define FDIM 144   // 16*9

__device__ __forceinline__ double meanc(int c){ return c==0?0.485:(c==1?0.456:0.406); }
__device__ __forceinline__ double stdc (int c){ return c==0?0.229:(c==1?0.224:0.225); }

// ---------------- generic f32 -> f64 converter (weights/biases)
__global__ __launch_bounds__(256) void k_cvt64(const float* __restrict__ s,
                                               double* __restrict__ d, int n){
  int i = blockIdx.x*256 + threadIdx.x;
  if (i < n) d[i] = (double)s[i];
}

// ---------------- prep: nq[2][3][120][120]  (b=0: norm(query); b=1: norm(avgpool2(key)))
__global__ __launch_bounds__(256) void k_prep(const float* __restrict__ query,
                                              const float* __restrict__ key,
                                              float* __restrict__ nq){
  int i = blockIdx.x*256 + threadIdx.x;
  if (i >= 2*3*L) return;
  int b = i/(3*L); int r = i - b*3*L; int c = r / L; int p = r - c*L;
  double v;
  if (b==0){
    v = (double)query[c*L + p];
  } else {
    int y = p / W0, x = p - y*W0;
    const float* kk = key + (size_t)c*(H1*W1);
    int yy = 2*y, xx = 2*x;
    v = 0.25*((double)kk[yy*W1+xx] + (double)kk[yy*W1+xx+1]
            + (double)kk[(yy+1)*W1+xx] + (double)kk[(yy+1)*W1+xx+1]);
  }
  nq[i] = (float)((v - meanc(c)) / stdc(c));
}

// cubic kernel, a = -0.75 (torch bicubic), double
__device__ __forceinline__ double cubw(double x){
  x = fabs(x);
  if (x <= 1.0)      return (1.25*x - 2.25)*x*x + 1.0;
  else if (x < 2.0)  return -0.75*(((x - 5.0)*x + 8.0)*x - 4.0);
  return 0.0;
}

// ---------------- bicubic x2 upsample, align_corners=True: up[2][3][240][240] <- nq
__global__ __launch_bounds__(256) void k_bicubic(const float* __restrict__ nq,
                                                 float* __restrict__ up){
  int i = blockIdx.x*256 + threadIdx.x;
  if (i >= 2*3*H1*W1) return;
  int bc = i/(H1*W1); int r = i - bc*H1*W1; int oy = r/W1, ox = r - oy*W1;
  double sy = (double)oy * (double)(H0-1) / (double)(H1-1);
  double sx = (double)ox * (double)(W0-1) / (double)(W1-1);
  int fy = (int)floor(sy); double ty = sy - (double)fy;
  int fx = (int)floor(sx); double tx = sx - (double)fx;
  double wy[4], wx[4]; int iy[4], ix[4];
  #pragma unroll
  for (int o=0;o<4;++o){
    wy[o] = cubw(ty - (double)(o-1));
    wx[o] = cubw(tx - (double)(o-1));
    int yv = fy + o - 1; iy[o] = min(max(yv,0),H0-1);
    int xv = fx + o - 1; ix[o] = min(max(xv,0),W0-1);
  }
  const float* src = nq + (size_t)bc*(H0*W0);
  double acc = 0.0;
  #pragma unroll
  for (int j=0;j<4;++j){
    double colv = 0.0;
    #pragma unroll
    for (int a=0;a<4;++a) colv += wy[a]*(double)src[iy[a]*W0 + ix[j]];
    acc += wx[j]*colv;
  }
  up[i] = (float)acc;
}

// ---------------- 3x3 conv, pad 1, ReLU, fp64 accumulation.
// grid: (tiles, CO/8, batch). 30x30 out tile, thread = 2x2 px * 8 oc.
template<int CIN, int CIC, int HW>
__global__ __launch_bounds__(256) void k_conv3x3(const float* __restrict__ in,
                                                 const double* __restrict__ w,
                                                 const double* __restrict__ bias,
                                                 float* __restrict__ out, int CO){
  constexpr int T = 30, TI = 32, TP = 33;
  constexpr int NT = HW / T;
  __shared__ float s_in[CIC][TI][TP];
  int tid = threadIdx.x;
  int tile = blockIdx.x; int trow = tile/NT;
  int ty0 = trow*T, tx0 = (tile - trow*NT)*T;
  int ocb = blockIdx.y*8; int b = blockIdx.z;
  const float* inb = in + (size_t)b*CIN*HW*HW;
  bool active = tid < 225;
  int tyy = (tid/15)*2, txx = (tid%15)*2;
  double acc[2][2][8];
  #pragma unroll
  for (int o=0;o<8;++o){
    double bv = bias[ocb+o];
    acc[0][0][o]=bv; acc[0][1][o]=bv; acc[1][0][o]=bv; acc[1][1][o]=bv;
  }
  for (int c0=0; c0<CIN; c0+=CIC){
    __syncthreads();
    for (int l=tid; l<CIC*TI*TI; l+=256){
      int ci = l/(TI*TI); int rr = (l/TI)%TI; int cc = l%TI;
      int gy = ty0+rr-1, gx = tx0+cc-1;
      float v = 0.f;
      if (gy>=0 && gy<HW && gx>=0 && gx<HW)
        v = inb[(size_t)(c0+ci)*HW*HW + gy*HW + gx];
      s_in[ci][rr][cc] = v;
    }
    __syncthreads();
    if (active){
      for (int ci=0; ci<CIC; ++ci){
        double tap[4][4];
        #pragma unroll
        for (int rr=0;rr<4;++rr)
          #pragma unroll
          for (int cc=0;cc<4;++cc) tap[rr][cc] = (double)s_in[ci][tyy+rr][txx+cc];
        const double* wp = w + ((size_t)ocb*CIN + (c0+ci))*9;
        #pragma unroll
        for (int t=0;t<9;++t){
          const int ky = t/3, kx = t - ky*3;
          #pragma unroll
          for (int o=0;o<8;++o){
            double wv = wp[(size_t)o*CIN*9 + t];   // block-uniform -> scalar load
            acc[0][0][o] += tap[ky+0][kx+0]*wv;
            acc[0][1][o] += tap[ky+0][kx+1]*wv;
            acc[1][0][o] += tap[ky+1][kx+0]*wv;
            acc[1][1][o] += tap[ky+1][kx+1]*wv;
          }
        }
      }
    }
  }
  if (active){
    #pragma unroll
    for (int py=0;py<2;++py)
      #pragma unroll
      for (int px=0;px<2;++px){
        int gy = ty0+tyy+py, gx = tx0+txx+px;
        float* op = out + ((size_t)(b*CO+ocb)*HW + gy)*HW + gx;
        #pragma unroll
        for (int o=0;o<8;++o){
          double v = acc[py][px][o];
          op[(size_t)o*HW*HW] = (float)(v>0.0 ? v : 0.0);
        }
      }
  }
}

// ---------------- 2x2 max pool: (2,64,240,240) -> (2,64,120,120)  (exact)
__global__ __launch_bounds__(256) void k_maxpool(const float* __restrict__ in,
                                                 float* __restrict__ out){
  int i = blockIdx.x*256 + threadIdx.x;
  if (i >= 2*64*L) return;
  int bc = i / L; int p = i - bc*L; int y = p/W0, x = p - y*W0;
  const float* s = in + (size_t)bc*H1*W1;
  int yy = 2*y, xx = 2*x;
  out[i] = fmaxf(fmaxf(s[yy*W1+xx], s[yy*W1+xx+1]),
                 fmaxf(s[(yy+1)*W1+xx], s[(yy+1)*W1+xx+1]));
}

// ---------------- 1x1 conv 128->16 + LeakyReLU(0.2), fp64 accumulation
__global__ __launch_bounds__(256) void k_conv1x1(const float* __restrict__ in,
                                                 const double* __restrict__ wm,
                                                 const double* __restrict__ bm,
                                                 float* __restrict__ out){
  int i = blockIdx.x*256 + threadIdx.x;
  if (i >= 2*L) return;
  int b = i/L; int p = i - b*L;
  double a[16];
  #pragma unroll
  for (int o=0;o<16;++o) a[o] = bm[o];
  const float* src = in + (size_t)b*128*L + p;
  for (int ci=0; ci<128; ++ci){
    double v = (double)src[(size_t)ci*L];
    #pragma unroll
    for (int o=0;o<16;++o) a[o] += v * wm[o*128 + ci];  // uniform -> scalar load
  }
  float* dst = out + (size_t)b*16*L + p;
  #pragma unroll
  for (int o=0;o<16;++o){ double v=a[o]; dst[(size_t)o*L] = (float)(v>0.0 ? v : 0.2*v); }
}

// ---------------- im2col 3x3 pad1 + per-pixel L2 normalize (fp64) -> P[b][144][14400]
__global__ __launch_bounds__(256) void k_patches(const float* __restrict__ fm,
                                                 float* __restrict__ P){
  int i = blockIdx.x*256 + threadIdx.x;
  if (i >= 2*L) return;
  int b = i/L; int p = i - b*L; int y = p/W0, x = p - y*W0;
  const float* src = fm + (size_t)b*16*L;
  double ss = 0.0;
  for (int c=0;c<16;++c){
    #pragma unroll
    for (int dy=0;dy<3;++dy){
      int gy = y+dy-1;
      #pragma unroll
      for (int dx=0;dx<3;++dx){
        int gx = x+dx-1;
        double v = (gy>=0 && gy<H0 && gx>=0 && gx<W0) ? (double)src[c*L + gy*W0 + gx] : 0.0;
        ss += v*v;
      }
    }
  }
  double rn = 1.0 / fmax(sqrt(ss), 1e-12);
  float* dst = P + (size_t)b*FDIM*L + p;
  for (int c=0;c<16;++c){
    #pragma unroll
    for (int dy=0;dy<3;++dy){
      int gy = y+dy-1;
      #pragma unroll
      for (int dx=0;dx<3;++dx){
        int gx = x+dx-1;
        double v = (gy>=0 && gy<H0 && gx>=0 && gx<W0) ? (double)src[c*L + gy*W0 + gx] : 0.0;
        dst[(size_t)(c*9 + dy*3 + dx)*L] = (float)(v*rn);
      }
    }
  }
}

// ---------------- fused similarity matmul (fp64 acc) + per-query max/argmax
// block: 32 queries; threads 256 = 8 qt (x4 q) * 32 kt (x4 k); K chunk = 128
// argmax semantics: first occurrence of max (jnp.argmax). Per-thread scan is
// ascending in key index (strict >); cross-thread combine ties -> smaller index.
__global__ __launch_bounds__(256) void k_sim(const float* __restrict__ P,
                                             float* __restrict__ out){
  const float* Q = P;                       // [144][14400]
  const float* K = P + (size_t)FDIM*L;      // [144][14400]
  __shared__ __align__(16) float sq[FDIM][32];
  __shared__ __align__(16) float sk[72][128];
  __shared__ double smx[32][32];
  __shared__ int    smi[32][32];
  int tid = threadIdx.x; int q0 = blockIdx.x*32;
  int qt = tid & 7, kt = tid >> 3;
  for (int l=tid; l<FDIM*32; l+=256){
    int c = l>>5, qq = l&31;
    sq[c][qq] = Q[(size_t)c*L + q0 + qq];
  }
  double mx[4] = {-1e300,-1e300,-1e300,-1e300};
  int    mi[4] = {0,0,0,0};
  for (int k0=0; k0<L; k0+=128){
    double acc[4][4] = {};
    #pragma unroll
    for (int ch=0; ch<2; ++ch){
      __syncthreads();
      for (int l=tid; l<72*128; l+=256){
        int c = l>>7, kk = l&127;
        int kg = k0 + kk;
        sk[c][kk] = (kg < L) ? K[(size_t)(ch*72+c)*L + kg] : 0.f;
      }
      __syncthreads();
      #pragma unroll 2
      for (int c=0;c<72;++c){
        float4 qv = *(const float4*)&sq[ch*72+c][qt*4];
        float4 kv = *(const float4*)&sk[c][kt*4];
        double qd0=qv.x, qd1=qv.y, qd2=qv.z, qd3=qv.w;
        double kd0=kv.x, kd1=kv.y, kd2=kv.z, kd3=kv.w;
        acc[0][0]+=qd0*kd0; acc[0][1]+=qd0*kd1; acc[0][2]+=qd0*kd2; acc[0][3]+=qd0*kd3;
        acc[1][0]+=qd1*kd0; acc[1][1]+=qd1*kd1; acc[1][2]+=qd1*kd2; acc[1][3]+=qd1*kd3;
        acc[2][0]+=qd2*kd0; acc[2][1]+=qd2*kd1; acc[2][2]+=qd2*kd2; acc[2][3]+=qd2*kd3;
        acc[3][0]+=qd3*kd0; acc[3][1]+=qd3*kd1; acc[3][2]+=qd3*kd2; acc[3][3]+=qd3*kd3;
      }
    }
    int kbase = k0 + kt*4;
    #pragma unroll
    for (int j=0;j<4;++j){
      int kidx = kbase + j;
      if (kidx < L){
        #pragma unroll
        for (int iq=0;iq<4;++iq){
          double s = acc[iq][j];
          if (s > mx[iq]){ mx[iq] = s; mi[iq] = kidx; }   // ascending scan -> first occurrence
        }
      }
    }
  }
  __syncthreads();
  #pragma unroll
  for (int iq=0;iq<4;++iq){ smx[kt][qt*4+iq] = mx[iq]; smi[kt][qt*4+iq] = mi[iq]; }
  __syncthreads();
  if (tid < 32){
    double best = -1e300; int bi = 0x7fffffff;
    for (int k2=0;k2<32;++k2){
      double v = smx[k2][tid];
      int    ii = smi[k2][tid];
      if (v > best || (v == best && ii < bi)){ best = v; bi = ii; }  // min-index tie-break
    }
    out[q0 + tid] = (float)best;          // rel
    out[L + q0 + tid] = (float)bi;        // idx (exact in f32: < 2^24)
  }
}

extern "C" void kernel_launch(void* const* d_in, const int* in_sizes, int n_in,
                              void* d_out, int out_size, void* d_ws, size_t ws_size,
                              hipStream_t stream){
  const float* query = (const float*)d_in[0];
  const float* key   = (const float*)d_in[1];
  const float* w1 = (const float*)d_in[2];
  const float* b1 = (const float*)d_in[3];
  const float* w2 = (const float*)d_in[4];
  const float* b2 = (const float*)d_in[5];
  const float* w3 = (const float*)d_in[6];
  const float* b3 = (const float*)d_in[7];
  const float* wm = (const float*)d_in[8];
  const float* bm = (const float*)d_in[9];
  float* out = (float*)d_out;

  // ---- workspace layout ----
  // doubles first (d_ws is 256B-aligned): 114,640 doubles of converted weights
  double* wd = (double*)d_ws;
  double* wd1 = wd;            // 1728
  double* bd1 = wd + 1728;     // 64
  double* wd2 = wd + 1792;     // 36864
  double* bd2 = wd + 38656;    // 64
  double* wd3 = wd + 38720;    // 73728
  double* bd3 = wd + 112448;   // 128
  double* wdm = wd + 112576;   // 2048
  double* bdm = wd + 114624;   // 16  -> total 114640 doubles = 229280 floats
  float* fbase = (float*)d_ws + 230400;
  float* nq = fbase;                            //   86400
  float* up = nq + 86400;                       //  345600
  float* A  = up + 345600;                      // 7372800  (conv1 out)
  float* Bf = A  + 7372800;                     // 7372800  (conv2 out)
  float* C  = A;                                // 1843200  (pool out; A dead after conv2)
  float* D  = A + 1843200;                      // 3686400  (conv3 out)
  float* FM = A + 1843200 + 3686400;            //  460800  (1x1 out)
  float* P  = Bf;                               // 4147200  (patches; Bf dead after pool)

  k_cvt64<<<(1728+255)/256, 256, 0, stream>>>(w1, wd1, 1728);
  k_cvt64<<<1, 256, 0, stream>>>(b1, bd1, 64);
  k_cvt64<<<(36864+255)/256, 256, 0, stream>>>(w2, wd2, 36864);
  k_cvt64<<<1, 256, 0, stream>>>(b2, bd2, 64);
  k_cvt64<<<(73728+255)/256, 256, 0, stream>>>(w3, wd3, 73728);
  k_cvt64<<<1, 256, 0, stream>>>(b3, bd3, 128);
  k_cvt64<<<(2048+255)/256, 256, 0, stream>>>(wm, wdm, 2048);
  k_cvt64<<<1, 256, 0, stream>>>(bm, bdm, 16);

  k_prep   <<<(2*3*L + 255)/256, 256, 0, stream>>>(query, key, nq);
  k_bicubic<<<(2*3*H1*W1 + 255)/256, 256, 0, stream>>>(nq, up);
  k_conv3x3<3,3,240><<<dim3(64,8,2), 256, 0, stream>>>(up, wd1, bd1, A, 64);
  k_conv3x3<64,4,240><<<dim3(64,8,2), 256, 0, stream>>>(A, wd2, bd2, Bf, 64);
  k_maxpool<<<(2*64*L + 255)/256, 256, 0, stream>>>(Bf, C);
  k_conv3x3<64,4,120><<<dim3(16,16,2), 256, 0, stream>>>(C, wd3, bd3, D, 128);
  k_conv1x1<<<(2*L + 255)/256, 256, 0, stream>>>(D, wdm, bdm, FM);
  k_patches<<<(2*L + 255)/256, 256, 0, stream>>>(FM, P);
  k_sim    <<<450, 256, 0, stream>>>(P, out);
}

// Round 4
// 2114.954 us; speedup vs baseline: 1.8477x; 1.8477x over previous
//
#include <hip/hip_runtime.h>
#include <math.h>

#define H0 120
#define W0 120
#define H1 240
#define W1 240
#define L  14400   // 120*120
#define FDIM 144   // 16*9

#define NSEG   4
#define SEGLEN 3600     // L / NSEG
#define QB     32
#define CHUNK  256
#define NCH    15       // ceil(3600/256): 14 full + one 16-key tail

__device__ __forceinline__ double meanc(int c){ return c==0?0.485:(c==1?0.456:0.406); }
__device__ __forceinline__ double stdc (int c){ return c==0?0.229:(c==1?0.224:0.225); }

// ---------------- all weights f32 -> f64 in one launch
__global__ __launch_bounds__(256) void k_cvt_all(const float* __restrict__ w1, const float* __restrict__ b1,
                                                 const float* __restrict__ w2, const float* __restrict__ b2,
                                                 const float* __restrict__ w3, const float* __restrict__ b3,
                                                 const float* __restrict__ wm, const float* __restrict__ bm,
                                                 double* __restrict__ wd){
  int i = blockIdx.x*256 + threadIdx.x;
  if (i >= 114640) return;
  float v;
  if      (i < 1728)   v = w1[i];
  else if (i < 1792)   v = b1[i-1728];
  else if (i < 38656)  v = w2[i-1792];
  else if (i < 38720)  v = b2[i-38656];
  else if (i < 112448) v = w3[i-38720];
  else if (i < 112576) v = b3[i-112448];
  else if (i < 114624) v = wm[i-112576];
  else                 v = bm[i-114624];
  wd[i] = (double)v;
}

// ---------------- prep: nq[2][3][120][120]  (b=0: norm(query); b=1: norm(avgpool2(key)))
__global__ __launch_bounds__(256) void k_prep(const float* __restrict__ query,
                                              const float* __restrict__ key,
                                              float* __restrict__ nq){
  int i = blockIdx.x*256 + threadIdx.x;
  if (i >= 2*3*L) return;
  int b = i/(3*L); int r = i - b*3*L; int c = r / L; int p = r - c*L;
  double v;
  if (b==0){
    v = (double)query[c*L + p];
  } else {
    int y = p / W0, x = p - y*W0;
    const float* kk = key + (size_t)c*(H1*W1);
    int yy = 2*y, xx = 2*x;
    v = 0.25*((double)kk[yy*W1+xx] + (double)kk[yy*W1+xx+1]
            + (double)kk[(yy+1)*W1+xx] + (double)kk[(yy+1)*W1+xx+1]);
  }
  nq[i] = (float)((v - meanc(c)) / stdc(c));
}

// cubic kernel, a = -0.75 (torch bicubic), double
__device__ __forceinline__ double cubw(double x){
  x = fabs(x);
  if (x <= 1.0)      return (1.25*x - 2.25)*x*x + 1.0;
  else if (x < 2.0)  return -0.75*(((x - 5.0)*x + 8.0)*x - 4.0);
  return 0.0;
}

// ---------------- bicubic x2 upsample, align_corners=True: up[2][3][240][240] <- nq
__global__ __launch_bounds__(256) void k_bicubic(const float* __restrict__ nq,
                                                 float* __restrict__ up){
  int i = blockIdx.x*256 + threadIdx.x;
  if (i >= 2*3*H1*W1) return;
  int bc = i/(H1*W1); int r = i - bc*H1*W1; int oy = r/W1, ox = r - oy*W1;
  double sy = (double)oy * (double)(H0-1) / (double)(H1-1);
  double sx = (double)ox * (double)(W0-1) / (double)(W1-1);
  int fy = (int)floor(sy); double ty = sy - (double)fy;
  int fx = (int)floor(sx); double tx = sx - (double)fx;
  double wy[4], wx[4]; int iy[4], ix[4];
  #pragma unroll
  for (int o=0;o<4;++o){
    wy[o] = cubw(ty - (double)(o-1));
    wx[o] = cubw(tx - (double)(o-1));
    int yv = fy + o - 1; iy[o] = min(max(yv,0),H0-1);
    int xv = fx + o - 1; ix[o] = min(max(xv,0),W0-1);
  }
  const float* src = nq + (size_t)bc*(H0*W0);
  double acc = 0.0;
  #pragma unroll
  for (int j=0;j<4;++j){
    double colv = 0.0;
    #pragma unroll
    for (int a=0;a<4;++a) colv += wy[a]*(double)src[iy[a]*W0 + ix[j]];
    acc += wx[j]*colv;
  }
  up[i] = (float)acc;
}

// ---------------- 3x3 conv, pad 1, ReLU, fp64 accumulation.
// grid: (tiles, CO/8, batch). 30x30 out tile, thread = 2x2 px * 8 oc.
template<int CIN, int CIC, int HW>
__global__ __launch_bounds__(256) void k_conv3x3(const float* __restrict__ in,
                                                 const double* __restrict__ w,
                                                 const double* __restrict__ bias,
                                                 float* __restrict__ out, int CO){
  constexpr int T = 30, TI = 32, TP = 33;
  constexpr int NT = HW / T;
  __shared__ float s_in[CIC][TI][TP];
  int tid = threadIdx.x;
  int tile = blockIdx.x; int trow = tile/NT;
  int ty0 = trow*T, tx0 = (tile - trow*NT)*T;
  int ocb = blockIdx.y*8; int b = blockIdx.z;
  const float* inb = in + (size_t)b*CIN*HW*HW;
  bool active = tid < 225;
  int tyy = (tid/15)*2, txx = (tid%15)*2;
  double acc[2][2][8];
  #pragma unroll
  for (int o=0;o<8;++o){
    double bv = bias[ocb+o];
    acc[0][0][o]=bv; acc[0][1][o]=bv; acc[1][0][o]=bv; acc[1][1][o]=bv;
  }
  for (int c0=0; c0<CIN; c0+=CIC){
    __syncthreads();
    for (int l=tid; l<CIC*TI*TI; l+=256){
      int ci = l/(TI*TI); int rr = (l/TI)%TI; int cc = l%TI;
      int gy = ty0+rr-1, gx = tx0+cc-1;
      float v = 0.f;
      if (gy>=0 && gy<HW && gx>=0 && gx<HW)
        v = inb[(size_t)(c0+ci)*HW*HW + gy*HW + gx];
      s_in[ci][rr][cc] = v;
    }
    __syncthreads();
    if (active){
      for (int ci=0; ci<CIC; ++ci){
        double tap[4][4];
        #pragma unroll
        for (int rr=0;rr<4;++rr)
          #pragma unroll
          for (int cc=0;cc<4;++cc) tap[rr][cc] = (double)s_in[ci][tyy+rr][txx+cc];
        const double* wp = w + ((size_t)ocb*CIN + (c0+ci))*9;
        #pragma unroll
        for (int t=0;t<9;++t){
          const int ky = t/3, kx = t - ky*3;
          #pragma unroll
          for (int o=0;o<8;++o){
            double wv = wp[(size_t)o*CIN*9 + t];   // block-uniform -> scalar load
            acc[0][0][o] += tap[ky+0][kx+0]*wv;
            acc[0][1][o] += tap[ky+0][kx+1]*wv;
            acc[1][0][o] += tap[ky+1][kx+0]*wv;
            acc[1][1][o] += tap[ky+1][kx+1]*wv;
          }
        }
      }
    }
  }
  if (active){
    #pragma unroll
    for (int py=0;py<2;++py)
      #pragma unroll
      for (int px=0;px<2;++px){
        int gy = ty0+tyy+py, gx = tx0+txx+px;
        float* op = out + ((size_t)(b*CO+ocb)*HW + gy)*HW + gx;
        #pragma unroll
        for (int o=0;o<8;++o){
          double v = acc[py][px][o];
          op[(size_t)o*HW*HW] = (float)(v>0.0 ? v : 0.0);
        }
      }
  }
}

// ---------------- 2x2 max pool: (2,64,240,240) -> (2,64,120,120)  (exact)
__global__ __launch_bounds__(256) void k_maxpool(const float* __restrict__ in,
                                                 float* __restrict__ out){
  int i = blockIdx.x*256 + threadIdx.x;
  if (i >= 2*64*L) return;
  int bc = i / L; int p = i - bc*L; int y = p/W0, x = p - y*W0;
  const float* s = in + (size_t)bc*H1*W1;
  int yy = 2*y, xx = 2*x;
  out[i] = fmaxf(fmaxf(s[yy*W1+xx], s[yy*W1+xx+1]),
                 fmaxf(s[(yy+1)*W1+xx], s[(yy+1)*W1+xx+1]));
}

// ---------------- 1x1 conv 128->16 + LeakyReLU(0.2), fp64 accumulation
__global__ __launch_bounds__(256) void k_conv1x1(const float* __restrict__ in,
                                                 const double* __restrict__ wm,
                                                 const double* __restrict__ bm,
                                                 float* __restrict__ out){
  int i = blockIdx.x*256 + threadIdx.x;
  if (i >= 2*L) return;
  int b = i/L; int p = i - b*L;
  double a[16];
  #pragma unroll
  for (int o=0;o<16;++o) a[o] = bm[o];
  const float* src = in + (size_t)b*128*L + p;
  for (int ci=0; ci<128; ++ci){
    double v = (double)src[(size_t)ci*L];
    #pragma unroll
    for (int o=0;o<16;++o) a[o] += v * wm[o*128 + ci];  // uniform -> scalar load
  }
  float* dst = out + (size_t)b*16*L + p;
  #pragma unroll
  for (int o=0;o<16;++o){ double v=a[o]; dst[(size_t)o*L] = (float)(v>0.0 ? v : 0.2*v); }
}

// ---------------- im2col 3x3 pad1 + per-pixel L2 normalize (fp64) -> P[b][144][14400]
__global__ __launch_bounds__(256) void k_patches(const float* __restrict__ fm,
                                                 float* __restrict__ P){
  int i = blockIdx.x*256 + threadIdx.x;
  if (i >= 2*L) return;
  int b = i/L; int p = i - b*L; int y = p/W0, x = p - y*W0;
  const float* src = fm + (size_t)b*16*L;
  double ss = 0.0;
  for (int c=0;c<16;++c){
    #pragma unroll
    for (int dy=0;dy<3;++dy){
      int gy = y+dy-1;
      #pragma unroll
      for (int dx=0;dx<3;++dx){
        int gx = x+dx-1;
        double v = (gy>=0 && gy<H0 && gx>=0 && gx<W0) ? (double)src[c*L + gy*W0 + gx] : 0.0;
        ss += v*v;
      }
    }
  }
  double rn = 1.0 / fmax(sqrt(ss), 1e-12);
  float* dst = P + (size_t)b*FDIM*L + p;
  for (int c=0;c<16;++c){
    #pragma unroll
    for (int dy=0;dy<3;++dy){
      int gy = y+dy-1;
      #pragma unroll
      for (int dx=0;dx<3;++dx){
        int gx = x+dx-1;
        double v = (gy>=0 && gy<H0 && gx>=0 && gx<W0) ? (double)src[c*L + gy*W0 + gx] : 0.0;
        dst[(size_t)(c*9 + dy*3 + dx)*L] = (float)(v*rn);
      }
    }
  }
}

// ---------------- fused similarity matmul (fp64 acc) + per-(segment,query) max/argmax
// grid (450, 4): 32 queries x 3600-key segment per block. 256 thr = 8 qt (x4 q) * 32 kt (x8 k).
// Keys per chunk: 256 (staged as 4 stages of 36 c-rows, f32 in LDS; cvt to f64 in regs).
// argmax: per-thread ascending-key strict > keeps first occurrence; block combine breaks
// value ties by min index; segment partials reduced ascending in k_simred.
__global__ __launch_bounds__(256) void k_sim(const float* __restrict__ P,
                                             double* __restrict__ pm,
                                             int* __restrict__ pi){
  const float* Q  = P;                      // [144][14400]
  const float* Kp = P + (size_t)FDIM*L;     // [144][14400]
  __shared__ __align__(16) float sq[FDIM][QB];     // 18432 B
  __shared__ __align__(16) float sk[36][CHUNK];    // 36864 B
  int tid = threadIdx.x;
  int q0 = blockIdx.x*QB;
  int segbase = blockIdx.y*SEGLEN;
  int kend = segbase + SEGLEN;
  int qt = tid & 7;          // 8 groups x 4 queries
  int kt = tid >> 3;         // 32 groups x 8 keys
  for (int i = tid; i < FDIM*QB; i += 256){
    int c = i >> 5, qq = i & 31;
    sq[c][qq] = Q[(size_t)c*L + q0 + qq];
  }
  double mx[4] = {-1e300,-1e300,-1e300,-1e300};
  int    mi[4] = {0,0,0,0};
  for (int ci = 0; ci < NCH; ++ci){
    int k0 = segbase + ci*CHUNK;
    double acc[4][8];
    #pragma unroll
    for (int a=0;a<4;++a)
      #pragma unroll
      for (int b=0;b<8;++b) acc[a][b] = 0.0;
    for (int st = 0; st < 4; ++st){
      int c0 = st*36;
      __syncthreads();
      // stage 36 c-rows x 256 keys; tail-chunk columns beyond kend hold garbage
      // (valid memory, never compared) -> no guards needed
      #pragma unroll
      for (int r = 0; r < 9; ++r){
        int i4  = r*1024 + tid*4;
        int row = i4 >> 8;
        int col = i4 & 255;
        float4 v = *(const float4*)&Kp[(size_t)(c0+row)*L + k0 + col];
        *(float4*)&sk[row][col] = v;
      }
      __syncthreads();
      #pragma unroll 2
      for (int cc = 0; cc < 36; ++cc){
        float4 qv  = *(const float4*)&sq[c0+cc][qt*4];
        float4 kv0 = *(const float4*)&sk[cc][kt*8];
        float4 kv1 = *(const float4*)&sk[cc][kt*8+4];
        double qd[4] = {(double)qv.x,(double)qv.y,(double)qv.z,(double)qv.w};
        double kd[8] = {(double)kv0.x,(double)kv0.y,(double)kv0.z,(double)kv0.w,
                        (double)kv1.x,(double)kv1.y,(double)kv1.z,(double)kv1.w};
        #pragma unroll
        for (int iq=0;iq<4;++iq)
          #pragma unroll
          for (int j=0;j<8;++j)
            acc[iq][j] += qd[iq]*kd[j];
      }
    }
    int kbase = k0 + kt*8;
    #pragma unroll
    for (int j=0;j<8;++j){
      int kidx = kbase + j;
      if (kidx < kend){
        #pragma unroll
        for (int iq=0;iq<4;++iq){
          double s = acc[iq][j];
          if (s > mx[iq]){ mx[iq] = s; mi[iq] = kidx; }  // ascending -> first occurrence
        }
      }
    }
  }
  // block reduction, overlaying sq/sk (all compute done)
  __syncthreads();
  double* smx = (double*)&sq[0][0];   // 32*32*8 = 8192 B  (sq is 18432)
  int*    smi = (int*)&sk[0][0];      // 32*32*4 = 4096 B  (sk is 36864)
  #pragma unroll
  for (int iq=0;iq<4;++iq){
    smx[kt*QB + qt*4+iq] = mx[iq];
    smi[kt*QB + qt*4+iq] = mi[iq];
  }
  __syncthreads();
  if (tid < QB){
    double best = -1e300; int bi = 0x7fffffff;
    for (int k2=0;k2<32;++k2){
      double v  = smx[k2*QB + tid];
      int    ii = smi[k2*QB + tid];
      if (v > best || (v == best && ii < bi)){ best = v; bi = ii; }
    }
    pm[(size_t)blockIdx.y*L + q0 + tid] = best;
    pi[(size_t)blockIdx.y*L + q0 + tid] = bi;
  }
}

// ---------------- reduce 4 segment partials (ascending seg = ascending key index)
__global__ __launch_bounds__(256) void k_simred(const double* __restrict__ pm,
                                                const int* __restrict__ pi,
                                                float* __restrict__ out){
  int i = blockIdx.x*256 + threadIdx.x;
  if (i >= L) return;
  double best = -1e300; int bi = 0;
  for (int s=0;s<NSEG;++s){
    double v = pm[(size_t)s*L + i];
    int   ii = pi[(size_t)s*L + i];
    if (v > best){ best = v; bi = ii; }   // equal -> keep earlier seg (smaller idx)
  }
  out[i]     = (float)best;               // rel
  out[L + i] = (float)bi;                 // idx (exact in f32: < 2^24)
}

extern "C" void kernel_launch(void* const* d_in, const int* in_sizes, int n_in,
                              void* d_out, int out_size, void* d_ws, size_t ws_size,
                              hipStream_t stream){
  const float* query = (const float*)d_in[0];
  const float* key   = (const float*)d_in[1];
  const float* w1 = (const float*)d_in[2];
  const float* b1 = (const float*)d_in[3];
  const float* w2 = (const float*)d_in[4];
  const float* b2 = (const float*)d_in[5];
  const float* w3 = (const float*)d_in[6];
  const float* b3 = (const float*)d_in[7];
  const float* wm = (const float*)d_in[8];
  const float* bm = (const float*)d_in[9];
  float* out = (float*)d_out;

  // ---- workspace layout ----
  double* wd = (double*)d_ws;   // 114640 doubles of converted weights
  double* wd1 = wd;            // 1728
  double* bd1 = wd + 1728;     // 64
  double* wd2 = wd + 1792;     // 36864
  double* bd2 = wd + 38656;    // 64
  double* wd3 = wd + 38720;    // 73728
  double* bd3 = wd + 112448;   // 128
  double* wdm = wd + 112576;   // 2048
  double* bdm = wd + 114624;   // 16
  float* fbase = (float*)d_ws + 230400;
  float* nq = fbase;                            //   86400
  float* up = nq + 86400;                       //  345600
  float* A  = up + 345600;                      // 7372800  (conv1 out)
  float* Bf = A  + 7372800;                     // 7372800  (conv2 out)
  float* C  = A;                                // 1843200  (pool out; A dead after conv2)
  float* D  = A + 1843200;                      // 3686400  (conv3 out)
  float* FM = A + 1843200 + 3686400;            //  460800  (1x1 out)
  float* P  = Bf;                               // 4147200  (patches; Bf dead after pool)
  // sim partials overlay A (conv outputs dead by k_sim time): 4*14400 doubles + ints
  double* pm = (double*)A;                      // 57600 doubles = 115200 floats
  int*    pi = (int*)(A + 115200);              // 57600 ints

  k_cvt_all<<<(114640+255)/256, 256, 0, stream>>>(w1,b1,w2,b2,w3,b3,wm,bm, wd);

  k_prep   <<<(2*3*L + 255)/256, 256, 0, stream>>>(query, key, nq);
  k_bicubic<<<(2*3*H1*W1 + 255)/256, 256, 0, stream>>>(nq, up);
  k_conv3x3<3,3,240><<<dim3(64,8,2), 256, 0, stream>>>(up, wd1, bd1, A, 64);
  k_conv3x3<64,4,240><<<dim3(64,8,2), 256, 0, stream>>>(A, wd2, bd2, Bf, 64);
  k_maxpool<<<(2*64*L + 255)/256, 256, 0, stream>>>(Bf, C);
  k_conv3x3<64,4,120><<<dim3(16,16,2), 256, 0, stream>>>(C, wd3, bd3, D, 128);
  k_conv1x1<<<(2*L + 255)/256, 256, 0, stream>>>(D, wdm, bdm, FM);
  k_patches<<<(2*L + 255)/256, 256, 0, stream>>>(FM, P);
  k_sim    <<<dim3(450, NSEG), 256, 0, stream>>>(P, pm, pi);
  k_simred <<<(L + 255)/256, 256, 0, stream>>>(pm, pi, out);
}

// Round 5
// 1725.109 us; speedup vs baseline: 2.2652x; 1.2260x over previous
//
#include <hip/hip_runtime.h>
#include <math.h>

#define H0 120
#define W0 120
#define H1 240
#define W1 240
#define L  14400   // 120*120
#define FDIM 144   // 16*9

#define NSEG   4
#define SEGLEN 3600     // L / NSEG
#define QB     32
#define CHUNK  512
#define NCH    8        // chunks per segment: 7 full + one 16-key tail
#define NCHTOT 32       // NSEG * NCH
#define MARGIN 1e-3f    // >> 4*E_fp32 (~1.7e-5): captures fp64 winner + all exact ties

__device__ __forceinline__ double meanc(int c){ return c==0?0.485:(c==1?0.456:0.406); }
__device__ __forceinline__ double stdc (int c){ return c==0?0.229:(c==1?0.224:0.225); }

// ---------------- all weights f32 -> f64 in one launch
__global__ __launch_bounds__(256) void k_cvt_all(const float* __restrict__ w1, const float* __restrict__ b1,
                                                 const float* __restrict__ w2, const float* __restrict__ b2,
                                                 const float* __restrict__ w3, const float* __restrict__ b3,
                                                 const float* __restrict__ wm, const float* __restrict__ bm,
                                                 double* __restrict__ wd){
  int i = blockIdx.x*256 + threadIdx.x;
  if (i >= 114640) return;
  float v;
  if      (i < 1728)   v = w1[i];
  else if (i < 1792)   v = b1[i-1728];
  else if (i < 38656)  v = w2[i-1792];
  else if (i < 38720)  v = b2[i-38656];
  else if (i < 112448) v = w3[i-38720];
  else if (i < 112576) v = b3[i-112448];
  else if (i < 114624) v = wm[i-112576];
  else                 v = bm[i-114624];
  wd[i] = (double)v;
}

// ---------------- prep: nq[2][3][120][120]  (b=0: norm(query); b=1: norm(avgpool2(key)))
__global__ __launch_bounds__(256) void k_prep(const float* __restrict__ query,
                                              const float* __restrict__ key,
                                              float* __restrict__ nq){
  int i = blockIdx.x*256 + threadIdx.x;
  if (i >= 2*3*L) return;
  int b = i/(3*L); int r = i - b*3*L; int c = r / L; int p = r - c*L;
  double v;
  if (b==0){
    v = (double)query[c*L + p];
  } else {
    int y = p / W0, x = p - y*W0;
    const float* kk = key + (size_t)c*(H1*W1);
    int yy = 2*y, xx = 2*x;
    v = 0.25*((double)kk[yy*W1+xx] + (double)kk[yy*W1+xx+1]
            + (double)kk[(yy+1)*W1+xx] + (double)kk[(yy+1)*W1+xx+1]);
  }
  nq[i] = (float)((v - meanc(c)) / stdc(c));
}

// cubic kernel, a = -0.75 (torch bicubic), double
__device__ __forceinline__ double cubw(double x){
  x = fabs(x);
  if (x <= 1.0)      return (1.25*x - 2.25)*x*x + 1.0;
  else if (x < 2.0)  return -0.75*(((x - 5.0)*x + 8.0)*x - 4.0);
  return 0.0;
}

// ---------------- bicubic x2 upsample, align_corners=True: up[2][3][240][240] <- nq
__global__ __launch_bounds__(256) void k_bicubic(const float* __restrict__ nq,
                                                 float* __restrict__ up){
  int i = blockIdx.x*256 + threadIdx.x;
  if (i >= 2*3*H1*W1) return;
  int bc = i/(H1*W1); int r = i - bc*H1*W1; int oy = r/W1, ox = r - oy*W1;
  double sy = (double)oy * (double)(H0-1) / (double)(H1-1);
  double sx = (double)ox * (double)(W0-1) / (double)(W1-1);
  int fy = (int)floor(sy); double ty = sy - (double)fy;
  int fx = (int)floor(sx); double tx = sx - (double)fx;
  double wy[4], wx[4]; int iy[4], ix[4];
  #pragma unroll
  for (int o=0;o<4;++o){
    wy[o] = cubw(ty - (double)(o-1));
    wx[o] = cubw(tx - (double)(o-1));
    int yv = fy + o - 1; iy[o] = min(max(yv,0),H0-1);
    int xv = fx + o - 1; ix[o] = min(max(xv,0),W0-1);
  }
  const float* src = nq + (size_t)bc*(H0*W0);
  double acc = 0.0;
  #pragma unroll
  for (int j=0;j<4;++j){
    double colv = 0.0;
    #pragma unroll
    for (int a=0;a<4;++a) colv += wy[a]*(double)src[iy[a]*W0 + ix[j]];
    acc += wx[j]*colv;
  }
  up[i] = (float)acc;
}

// ---------------- 3x3 conv, pad 1, ReLU, fp64 accumulation.
// grid: (tiles, CO/8, batch). 30x30 out tile, thread = 2x2 px * 8 oc.
template<int CIN, int CIC, int HW>
__global__ __launch_bounds__(256) void k_conv3x3(const float* __restrict__ in,
                                                 const double* __restrict__ w,
                                                 const double* __restrict__ bias,
                                                 float* __restrict__ out, int CO){
  constexpr int T = 30, TI = 32, TP = 33;
  constexpr int NT = HW / T;
  __shared__ float s_in[CIC][TI][TP];
  int tid = threadIdx.x;
  int tile = blockIdx.x; int trow = tile/NT;
  int ty0 = trow*T, tx0 = (tile - trow*NT)*T;
  int ocb = blockIdx.y*8; int b = blockIdx.z;
  const float* inb = in + (size_t)b*CIN*HW*HW;
  bool active = tid < 225;
  int tyy = (tid/15)*2, txx = (tid%15)*2;
  double acc[2][2][8];
  #pragma unroll
  for (int o=0;o<8;++o){
    double bv = bias[ocb+o];
    acc[0][0][o]=bv; acc[0][1][o]=bv; acc[1][0][o]=bv; acc[1][1][o]=bv;
  }
  for (int c0=0; c0<CIN; c0+=CIC){
    __syncthreads();
    for (int l=tid; l<CIC*TI*TI; l+=256){
      int ci = l/(TI*TI); int rr = (l/TI)%TI; int cc = l%TI;
      int gy = ty0+rr-1, gx = tx0+cc-1;
      float v = 0.f;
      if (gy>=0 && gy<HW && gx>=0 && gx<HW)
        v = inb[(size_t)(c0+ci)*HW*HW + gy*HW + gx];
      s_in[ci][rr][cc] = v;
    }
    __syncthreads();
    if (active){
      for (int ci=0; ci<CIC; ++ci){
        double tap[4][4];
        #pragma unroll
        for (int rr=0;rr<4;++rr)
          #pragma unroll
          for (int cc=0;cc<4;++cc) tap[rr][cc] = (double)s_in[ci][tyy+rr][txx+cc];
        const double* wp = w + ((size_t)ocb*CIN + (c0+ci))*9;
        #pragma unroll
        for (int t=0;t<9;++t){
          const int ky = t/3, kx = t - ky*3;
          #pragma unroll
          for (int o=0;o<8;++o){
            double wv = wp[(size_t)o*CIN*9 + t];   // block-uniform -> scalar load
            acc[0][0][o] += tap[ky+0][kx+0]*wv;
            acc[0][1][o] += tap[ky+0][kx+1]*wv;
            acc[1][0][o] += tap[ky+1][kx+0]*wv;
            acc[1][1][o] += tap[ky+1][kx+1]*wv;
          }
        }
      }
    }
  }
  if (active){
    #pragma unroll
    for (int py=0;py<2;++py)
      #pragma unroll
      for (int px=0;px<2;++px){
        int gy = ty0+tyy+py, gx = tx0+txx+px;
        float* op = out + ((size_t)(b*CO+ocb)*HW + gy)*HW + gx;
        #pragma unroll
        for (int o=0;o<8;++o){
          double v = acc[py][px][o];
          op[(size_t)o*HW*HW] = (float)(v>0.0 ? v : 0.0);
        }
      }
  }
}

// ---------------- 2x2 max pool: (2,64,240,240) -> (2,64,120,120)  (exact)
__global__ __launch_bounds__(256) void k_maxpool(const float* __restrict__ in,
                                                 float* __restrict__ out){
  int i = blockIdx.x*256 + threadIdx.x;
  if (i >= 2*64*L) return;
  int bc = i / L; int p = i - bc*L; int y = p/W0, x = p - y*W0;
  const float* s = in + (size_t)bc*H1*W1;
  int yy = 2*y, xx = 2*x;
  out[i] = fmaxf(fmaxf(s[yy*W1+xx], s[yy*W1+xx+1]),
                 fmaxf(s[(yy+1)*W1+xx], s[(yy+1)*W1+xx+1]));
}

// ---------------- 1x1 conv 128->16 + LeakyReLU(0.2), fp64 accumulation
__global__ __launch_bounds__(256) void k_conv1x1(const float* __restrict__ in,
                                                 const double* __restrict__ wm,
                                                 const double* __restrict__ bm,
                                                 float* __restrict__ out){
  int i = blockIdx.x*256 + threadIdx.x;
  if (i >= 2*L) return;
  int b = i/L; int p = i - b*L;
  double a[16];
  #pragma unroll
  for (int o=0;o<16;++o) a[o] = bm[o];
  const float* src = in + (size_t)b*128*L + p;
  for (int ci=0; ci<128; ++ci){
    double v = (double)src[(size_t)ci*L];
    #pragma unroll
    for (int o=0;o<16;++o) a[o] += v * wm[o*128 + ci];  // uniform -> scalar load
  }
  float* dst = out + (size_t)b*16*L + p;
  #pragma unroll
  for (int o=0;o<16;++o){ double v=a[o]; dst[(size_t)o*L] = (float)(v>0.0 ? v : 0.2*v); }
}

// ---------------- im2col 3x3 pad1 + per-pixel L2 normalize (fp64) -> P[b][144][14400]
__global__ __launch_bounds__(256) void k_patches(const float* __restrict__ fm,
                                                 float* __restrict__ P){
  int i = blockIdx.x*256 + threadIdx.x;
  if (i >= 2*L) return;
  int b = i/L; int p = i - b*L; int y = p/W0, x = p - y*W0;
  const float* src = fm + (size_t)b*16*L;
  double ss = 0.0;
  for (int c=0;c<16;++c){
    #pragma unroll
    for (int dy=0;dy<3;++dy){
      int gy = y+dy-1;
      #pragma unroll
      for (int dx=0;dx<3;++dx){
        int gx = x+dx-1;
        double v = (gy>=0 && gy<H0 && gx>=0 && gx<W0) ? (double)src[c*L + gy*W0 + gx] : 0.0;
        ss += v*v;
      }
    }
  }
  double rn = 1.0 / fmax(sqrt(ss), 1e-12);
  float* dst = P + (size_t)b*FDIM*L + p;
  for (int c=0;c<16;++c){
    #pragma unroll
    for (int dy=0;dy<3;++dy){
      int gy = y+dy-1;
      #pragma unroll
      for (int dx=0;dx<3;++dx){
        int gx = x+dx-1;
        double v = (gy>=0 && gy<H0 && gx>=0 && gx<W0) ? (double)src[c*L + gy*W0 + gx] : 0.0;
        dst[(size_t)(c*9 + dy*3 + dx)*L] = (float)(v*rn);
      }
    }
  }
}

// ---------------- PASS 1: fp32 similarity scan -> per-(chunk,query) max
// grid (450, 4): 32 queries x 3600-key segment. 256 thr = 8 qt (x4 q) * 32 kt (x16 k).
// 512-key chunks staged as 8 stages of 18 c-rows f32 in LDS. Tail chunk columns are
// clamped duplicates (finite, never counted). fp32 dot error E <= ~1.7e-5 (unit vectors).
__global__ __launch_bounds__(256) void k_sim32(const float* __restrict__ P,
                                               float* __restrict__ cmax){
  const float* Q  = P;                      // [144][14400]
  const float* Kp = P + (size_t)FDIM*L;     // [144][14400]
  __shared__ __align__(16) float sq[FDIM][QB];     // 18432 B
  __shared__ __align__(16) float sk[18][CHUNK];    // 36864 B
  __shared__ float smx[32][QB];                    //  4096 B
  int tid = threadIdx.x;
  int q0 = blockIdx.x*QB;
  int segbase = blockIdx.y*SEGLEN;
  int kend = segbase + SEGLEN;
  int qt = tid & 7;          // 8 groups x 4 queries
  int kt = tid >> 3;         // 32 groups x 16 keys
  for (int i = tid; i < FDIM*QB; i += 256){
    int c = i >> 5, qq = i & 31;
    sq[c][qq] = Q[(size_t)c*L + q0 + qq];
  }
  for (int ci = 0; ci < NCH; ++ci){
    int k0 = segbase + ci*CHUNK;
    float acc[4][16];
    #pragma unroll
    for (int a=0;a<4;++a)
      #pragma unroll
      for (int b=0;b<16;++b) acc[a][b] = 0.f;
    for (int st = 0; st < 8; ++st){
      int c0 = st*18;
      __syncthreads();
      #pragma unroll
      for (int r = 0; r < 9; ++r){
        int i4  = r*1024 + tid*4;
        int row = i4 >> 9;
        int col = i4 & 511;
        int ka  = min(k0 + col, L-4);     // clamp: stay inside Kp (finite dupes)
        *(float4*)&sk[row][col] = *(const float4*)&Kp[(size_t)(c0+row)*L + ka];
      }
      __syncthreads();
      #pragma unroll 2
      for (int cc = 0; cc < 18; ++cc){
        float4 qv = *(const float4*)&sq[c0+cc][qt*4];
        const float* skr = &sk[cc][kt*16];
        float4 k0v = *(const float4*)&skr[0];
        float4 k1v = *(const float4*)&skr[4];
        float4 k2v = *(const float4*)&skr[8];
        float4 k3v = *(const float4*)&skr[12];
        float qa[4]  = {qv.x,qv.y,qv.z,qv.w};
        float ka[16] = {k0v.x,k0v.y,k0v.z,k0v.w, k1v.x,k1v.y,k1v.z,k1v.w,
                        k2v.x,k2v.y,k2v.z,k2v.w, k3v.x,k3v.y,k3v.z,k3v.w};
        #pragma unroll
        for (int iq=0;iq<4;++iq)
          #pragma unroll
          for (int j=0;j<16;++j)
            acc[iq][j] += qa[iq]*ka[j];
      }
    }
    // per-(chunk, query) max
    int kbase = k0 + kt*16;
    float cmx[4] = {-1e30f,-1e30f,-1e30f,-1e30f};
    #pragma unroll
    for (int j=0;j<16;++j){
      if (kbase + j < kend){
        #pragma unroll
        for (int iq=0;iq<4;++iq) cmx[iq] = fmaxf(cmx[iq], acc[iq][j]);
      }
    }
    #pragma unroll
    for (int iq=0;iq<4;++iq) smx[kt][qt*4+iq] = cmx[iq];
    __syncthreads();
    if (tid < QB){
      float m = -1e30f;
      for (int k2=0;k2<32;++k2) m = fmaxf(m, smx[k2][tid]);
      cmax[(size_t)(blockIdx.y*NCH + ci)*L + q0 + tid] = m;
    }
    // next iteration's first __syncthreads() protects smx/sk reuse
  }
}

// ---------------- PASS 2: fp64 rescore of flagged chunks + final max/argmax
// one block per query. Flag: chunkmax >= gmax32 - MARGIN (provably contains the fp64
// winner and all exact ties). Ascending chunk/key order; min-index on exact fp64 ties.
__global__ __launch_bounds__(256) void k_rescore(const float* __restrict__ P,
                                                 const float* __restrict__ cmax,
                                                 float* __restrict__ out){
  const float* Q  = P;
  const float* Kp = P + (size_t)FDIM*L;
  int q = blockIdx.x, tid = threadIdx.x;
  __shared__ float sq[FDIM];
  __shared__ float scm[NCHTOT];
  __shared__ float sgm;
  __shared__ double rv[256];
  __shared__ int   ri[256];
  if (tid < FDIM)   sq[tid]  = Q[(size_t)tid*L + q];
  if (tid < NCHTOT) scm[tid] = cmax[(size_t)tid*L + q];
  __syncthreads();
  if (tid == 0){
    float g = -1e30f;
    for (int c=0;c<NCHTOT;++c) g = fmaxf(g, scm[c]);
    sgm = g;
  }
  __syncthreads();
  float thr = sgm - MARGIN;
  double best = -1e300; int bi = 0x7fffffff;
  for (int g = 0; g < NCHTOT; ++g){
    if (scm[g] < thr) continue;
    int seg = g >> 3, ci = g & 7;
    int base  = seg*SEGLEN + ci*CHUNK;
    int valid = min(CHUNK, SEGLEN - ci*CHUNK);   // 512 or 16
    #pragma unroll
    for (int h = 0; h < CHUNK/256; ++h){
      int off = h*256 + tid;
      if (off < valid){
        int key = base + off;
        double a0=0.0, a1=0.0, a2=0.0, a3=0.0;
        for (int c=0;c<FDIM;c+=4){
          a0 += (double)sq[c+0]*(double)Kp[(size_t)(c+0)*L + key];
          a1 += (double)sq[c+1]*(double)Kp[(size_t)(c+1)*L + key];
          a2 += (double)sq[c+2]*(double)Kp[(size_t)(c+2)*L + key];
          a3 += (double)sq[c+3]*(double)Kp[(size_t)(c+3)*L + key];
        }
        double a = (a0+a1)+(a2+a3);
        if (a > best){ best = a; bi = key; }   // ascending keys -> first occurrence
      }
    }
  }
  rv[tid] = best; ri[tid] = bi;
  __syncthreads();
  for (int s = 128; s > 0; s >>= 1){
    if (tid < s){
      double v2 = rv[tid+s]; int i2 = ri[tid+s];
      if (v2 > rv[tid] || (v2 == rv[tid] && i2 < ri[tid])){ rv[tid] = v2; ri[tid] = i2; }
    }
    __syncthreads();
  }
  if (tid == 0){
    out[q]     = (float)rv[0];     // rel
    out[L + q] = (float)ri[0];     // idx (exact in f32: < 2^24)
  }
}

extern "C" void kernel_launch(void* const* d_in, const int* in_sizes, int n_in,
                              void* d_out, int out_size, void* d_ws, size_t ws_size,
                              hipStream_t stream){
  const float* query = (const float*)d_in[0];
  const float* key   = (const float*)d_in[1];
  const float* w1 = (const float*)d_in[2];
  const float* b1 = (const float*)d_in[3];
  const float* w2 = (const float*)d_in[4];
  const float* b2 = (const float*)d_in[5];
  const float* w3 = (const float*)d_in[6];
  const float* b3 = (const float*)d_in[7];
  const float* wm = (const float*)d_in[8];
  const float* bm = (const float*)d_in[9];
  float* out = (float*)d_out;

  // ---- workspace layout ----
  double* wd = (double*)d_ws;   // 114640 doubles of converted weights
  double* wd1 = wd;            // 1728
  double* bd1 = wd + 1728;     // 64
  double* wd2 = wd + 1792;     // 36864
  double* bd2 = wd + 38656;    // 64
  double* wd3 = wd + 38720;    // 73728
  double* bd3 = wd + 112448;   // 128
  double* wdm = wd + 112576;   // 2048
  double* bdm = wd + 114624;   // 16
  float* fbase = (float*)d_ws + 230400;
  float* nq = fbase;                            //   86400
  float* up = nq + 86400;                       //  345600
  float* A  = up + 345600;                      // 7372800  (conv1 out)
  float* Bf = A  + 7372800;                     // 7372800  (conv2 out)
  float* C  = A;                                // 1843200  (pool out; A dead after conv2)
  float* D  = A + 1843200;                      // 3686400  (conv3 out)
  float* FM = A + 1843200 + 3686400;            //  460800  (1x1 out)
  float* P  = Bf;                               // 4147200  (patches; Bf dead after pool)
  float* cmax = A;                              // 460800   (A region dead after k_patches)

  k_cvt_all<<<(114640+255)/256, 256, 0, stream>>>(w1,b1,w2,b2,w3,b3,wm,bm, wd);

  k_prep   <<<(2*3*L + 255)/256, 256, 0, stream>>>(query, key, nq);
  k_bicubic<<<(2*3*H1*W1 + 255)/256, 256, 0, stream>>>(nq, up);
  k_conv3x3<3,3,240><<<dim3(64,8,2), 256, 0, stream>>>(up, wd1, bd1, A, 64);
  k_conv3x3<64,4,240><<<dim3(64,8,2), 256, 0, stream>>>(A, wd2, bd2, Bf, 64);
  k_maxpool<<<(2*64*L + 255)/256, 256, 0, stream>>>(Bf, C);
  k_conv3x3<64,4,120><<<dim3(16,16,2), 256, 0, stream>>>(C, wd3, bd3, D, 128);
  k_conv1x1<<<(2*L + 255)/256, 256, 0, stream>>>(D, wdm, bdm, FM);
  k_patches<<<(2*L + 255)/256, 256, 0, stream>>>(FM, P);
  k_sim32  <<<dim3(450, NSEG), 256, 0, stream>>>(P, cmax);
  k_rescore<<<L, 256, 0, stream>>>(P, cmax, out);
}

// Round 6
// 1495.290 us; speedup vs baseline: 2.6133x; 1.1537x over previous
//
#include <hip/hip_runtime.h>
#include <math.h>

#define H0 120
#define W0 120
#define H1 240
#define W1 240
#define L  14400   // 120*120
#define FDIM 144   // 16*9
#define CPAD 160   // FDIM padded to 5*32
#define LPAD 14464 // keys padded to 113*128 (dups of key L-1)

#define KC    128     // keys per chunk (flag granularity)
#define NCHT  113     // total chunks = LPAD/KC
#define NCHB  8       // chunks per block (grid.y = 15)
#define MARGIN 4e-3f  // >= 2*E_f16 (E <= ~1.5e-3 worst case incl. subnormal flush)

typedef _Float16 half8 __attribute__((ext_vector_type(8)));
typedef float    f32x4 __attribute__((ext_vector_type(4)));

__device__ __forceinline__ double meanc(int c){ return c==0?0.485:(c==1?0.456:0.406); }
__device__ __forceinline__ double stdc (int c){ return c==0?0.229:(c==1?0.224:0.225); }

// ---------------- all weights f32 -> f64 in one launch
__global__ __launch_bounds__(256) void k_cvt_all(const float* __restrict__ w1, const float* __restrict__ b1,
                                                 const float* __restrict__ w2, const float* __restrict__ b2,
                                                 const float* __restrict__ w3, const float* __restrict__ b3,
                                                 const float* __restrict__ wm, const float* __restrict__ bm,
                                                 double* __restrict__ wd){
  int i = blockIdx.x*256 + threadIdx.x;
  if (i >= 114640) return;
  float v;
  if      (i < 1728)   v = w1[i];
  else if (i < 1792)   v = b1[i-1728];
  else if (i < 38656)  v = w2[i-1792];
  else if (i < 38720)  v = b2[i-38656];
  else if (i < 112448) v = w3[i-38720];
  else if (i < 112576) v = b3[i-112448];
  else if (i < 114624) v = wm[i-112576];
  else                 v = bm[i-114624];
  wd[i] = (double)v;
}

// ---------------- prep: nq[2][3][120][120]  (b=0: norm(query); b=1: norm(avgpool2(key)))
__global__ __launch_bounds__(256) void k_prep(const float* __restrict__ query,
                                              const float* __restrict__ key,
                                              float* __restrict__ nq){
  int i = blockIdx.x*256 + threadIdx.x;
  if (i >= 2*3*L) return;
  int b = i/(3*L); int r = i - b*3*L; int c = r / L; int p = r - c*L;
  double v;
  if (b==0){
    v = (double)query[c*L + p];
  } else {
    int y = p / W0, x = p - y*W0;
    const float* kk = key + (size_t)c*(H1*W1);
    int yy = 2*y, xx = 2*x;
    v = 0.25*((double)kk[yy*W1+xx] + (double)kk[yy*W1+xx+1]
            + (double)kk[(yy+1)*W1+xx] + (double)kk[(yy+1)*W1+xx+1]);
  }
  nq[i] = (float)((v - meanc(c)) / stdc(c));
}

// cubic kernel, a = -0.75 (torch bicubic), double
__device__ __forceinline__ double cubw(double x){
  x = fabs(x);
  if (x <= 1.0)      return (1.25*x - 2.25)*x*x + 1.0;
  else if (x < 2.0)  return -0.75*(((x - 5.0)*x + 8.0)*x - 4.0);
  return 0.0;
}

// ---------------- bicubic x2 upsample, align_corners=True: up[2][3][240][240] <- nq
__global__ __launch_bounds__(256) void k_bicubic(const float* __restrict__ nq,
                                                 float* __restrict__ up){
  int i = blockIdx.x*256 + threadIdx.x;
  if (i >= 2*3*H1*W1) return;
  int bc = i/(H1*W1); int r = i - bc*H1*W1; int oy = r/W1, ox = r - oy*W1;
  double sy = (double)oy * (double)(H0-1) / (double)(H1-1);
  double sx = (double)ox * (double)(W0-1) / (double)(W1-1);
  int fy = (int)floor(sy); double ty = sy - (double)fy;
  int fx = (int)floor(sx); double tx = sx - (double)fx;
  double wy[4], wx[4]; int iy[4], ix[4];
  #pragma unroll
  for (int o=0;o<4;++o){
    wy[o] = cubw(ty - (double)(o-1));
    wx[o] = cubw(tx - (double)(o-1));
    int yv = fy + o - 1; iy[o] = min(max(yv,0),H0-1);
    int xv = fx + o - 1; ix[o] = min(max(xv,0),W0-1);
  }
  const float* src = nq + (size_t)bc*(H0*W0);
  double acc = 0.0;
  #pragma unroll
  for (int j=0;j<4;++j){
    double colv = 0.0;
    #pragma unroll
    for (int a=0;a<4;++a) colv += wy[a]*(double)src[iy[a]*W0 + ix[j]];
    acc += wx[j]*colv;
  }
  up[i] = (float)acc;
}

// ---------------- 3x3 conv, pad 1, ReLU, fp64 accumulation.
template<int CIN, int CIC, int HW>
__global__ __launch_bounds__(256) void k_conv3x3(const float* __restrict__ in,
                                                 const double* __restrict__ w,
                                                 const double* __restrict__ bias,
                                                 float* __restrict__ out, int CO){
  constexpr int T = 30, TI = 32, TP = 33;
  constexpr int NT = HW / T;
  __shared__ float s_in[CIC][TI][TP];
  int tid = threadIdx.x;
  int tile = blockIdx.x; int trow = tile/NT;
  int ty0 = trow*T, tx0 = (tile - trow*NT)*T;
  int ocb = blockIdx.y*8; int b = blockIdx.z;
  const float* inb = in + (size_t)b*CIN*HW*HW;
  bool active = tid < 225;
  int tyy = (tid/15)*2, txx = (tid%15)*2;
  double acc[2][2][8];
  #pragma unroll
  for (int o=0;o<8;++o){
    double bv = bias[ocb+o];
    acc[0][0][o]=bv; acc[0][1][o]=bv; acc[1][0][o]=bv; acc[1][1][o]=bv;
  }
  for (int c0=0; c0<CIN; c0+=CIC){
    __syncthreads();
    for (int l=tid; l<CIC*TI*TI; l+=256){
      int ci = l/(TI*TI); int rr = (l/TI)%TI; int cc = l%TI;
      int gy = ty0+rr-1, gx = tx0+cc-1;
      float v = 0.f;
      if (gy>=0 && gy<HW && gx>=0 && gx<HW)
        v = inb[(size_t)(c0+ci)*HW*HW + gy*HW + gx];
      s_in[ci][rr][cc] = v;
    }
    __syncthreads();
    if (active){
      for (int ci=0; ci<CIC; ++ci){
        double tap[4][4];
        #pragma unroll
        for (int rr=0;rr<4;++rr)
          #pragma unroll
          for (int cc=0;cc<4;++cc) tap[rr][cc] = (double)s_in[ci][tyy+rr][txx+cc];
        const double* wp = w + ((size_t)ocb*CIN + (c0+ci))*9;
        #pragma unroll
        for (int t=0;t<9;++t){
          const int ky = t/3, kx = t - ky*3;
          #pragma unroll
          for (int o=0;o<8;++o){
            double wv = wp[(size_t)o*CIN*9 + t];   // block-uniform -> scalar load
            acc[0][0][o] += tap[ky+0][kx+0]*wv;
            acc[0][1][o] += tap[ky+0][kx+1]*wv;
            acc[1][0][o] += tap[ky+1][kx+0]*wv;
            acc[1][1][o] += tap[ky+1][kx+1]*wv;
          }
        }
      }
    }
  }
  if (active){
    #pragma unroll
    for (int py=0;py<2;++py)
      #pragma unroll
      for (int px=0;px<2;++px){
        int gy = ty0+tyy+py, gx = tx0+txx+px;
        float* op = out + ((size_t)(b*CO+ocb)*HW + gy)*HW + gx;
        #pragma unroll
        for (int o=0;o<8;++o){
          double v = acc[py][px][o];
          op[(size_t)o*HW*HW] = (float)(v>0.0 ? v : 0.0);
        }
      }
  }
}

// ---------------- 2x2 max pool: (2,64,240,240) -> (2,64,120,120)  (exact)
__global__ __launch_bounds__(256) void k_maxpool(const float* __restrict__ in,
                                                 float* __restrict__ out){
  int i = blockIdx.x*256 + threadIdx.x;
  if (i >= 2*64*L) return;
  int bc = i / L; int p = i - bc*L; int y = p/W0, x = p - y*W0;
  const float* s = in + (size_t)bc*H1*W1;
  int yy = 2*y, xx = 2*x;
  out[i] = fmaxf(fmaxf(s[yy*W1+xx], s[yy*W1+xx+1]),
                 fmaxf(s[(yy+1)*W1+xx], s[(yy+1)*W1+xx+1]));
}

// ---------------- 1x1 conv 128->16 + LeakyReLU(0.2), fp64 accumulation
__global__ __launch_bounds__(256) void k_conv1x1(const float* __restrict__ in,
                                                 const double* __restrict__ wm,
                                                 const double* __restrict__ bm,
                                                 float* __restrict__ out){
  int i = blockIdx.x*256 + threadIdx.x;
  if (i >= 2*L) return;
  int b = i/L; int p = i - b*L;
  double a[16];
  #pragma unroll
  for (int o=0;o<16;++o) a[o] = bm[o];
  const float* src = in + (size_t)b*128*L + p;
  for (int ci=0; ci<128; ++ci){
    double v = (double)src[(size_t)ci*L];
    #pragma unroll
    for (int o=0;o<16;++o) a[o] += v * wm[o*128 + ci];  // uniform -> scalar load
  }
  float* dst = out + (size_t)b*16*L + p;
  #pragma unroll
  for (int o=0;o<16;++o){ double v=a[o]; dst[(size_t)o*L] = (float)(v>0.0 ? v : 0.2*v); }
}

// ---------------- im2col 3x3 pad1 + per-pixel L2 normalize (fp64), pixel-major outputs:
// Tq16/Tk16 [row][160] f16 (c padded with zeros), Tq32/Tk32 [row][160] f32.
// Threads >= 2L write dup rows (key L-1) into Tk rows 14400..14463.
__global__ __launch_bounds__(256) void k_patches(const float* __restrict__ fm,
                                                 _Float16* __restrict__ Tq16,
                                                 _Float16* __restrict__ Tk16,
                                                 float* __restrict__ Tq32,
                                                 float* __restrict__ Tk32){
  int i = blockIdx.x*256 + threadIdx.x;
  if (i >= 2*L + (LPAD - L)) return;
  int b, p, row;
  if (i < 2*L){ b = i / L; p = i - b*L; row = p; }
  else        { b = 1; p = L - 1; row = L + (i - 2*L); }
  int y = p/W0, x = p - y*W0;
  const float* src = fm + (size_t)b*16*L;
  double ss = 0.0;
  for (int c=0;c<16;++c){
    #pragma unroll
    for (int dy=0;dy<3;++dy){
      int gy = y+dy-1;
      #pragma unroll
      for (int dx=0;dx<3;++dx){
        int gx = x+dx-1;
        double v = (gy>=0 && gy<H0 && gx>=0 && gx<W0) ? (double)src[c*L + gy*W0 + gx] : 0.0;
        ss += v*v;
      }
    }
  }
  double rn = 1.0 / fmax(sqrt(ss), 1e-12);
  _Float16* d16 = (b==0 ? Tq16 : Tk16) + (size_t)row*CPAD;
  float*    d32 = (b==0 ? Tq32 : Tk32) + (size_t)row*CPAD;
  for (int c=0;c<16;++c){
    #pragma unroll
    for (int dy=0;dy<3;++dy){
      int gy = y+dy-1;
      #pragma unroll
      for (int dx=0;dx<3;++dx){
        int gx = x+dx-1;
        double v = (gy>=0 && gy<H0 && gx>=0 && gx<W0) ? (double)src[c*L + gy*W0 + gx] : 0.0;
        float f = (float)(v*rn);
        int idx = c*9 + dy*3 + dx;
        d32[idx] = f;
        d16[idx] = (_Float16)f;
      }
    }
  }
  for (int c=FDIM;c<CPAD;++c){ d32[c] = 0.f; d16[c] = (_Float16)0.f; }
}

// ---------------- PASS 1: f16 MFMA similarity scan -> per-(chunk,query) max
// grid (150, 15). Block: 96 q x (8 chunks of 128 keys). 4 waves: wk=wid&1 (64 keys),
// wq=wid>>1 (48 q). Q fragments persistent in VGPRs; K chunk staged frag-major in LDS
// via global_load_lds (conflict-free ds_read_b128). Keys are MFMA A-rows, queries are
// B-cols (C/D col=lane&15 verified layout); chunk-max over keys absorbs any A-row
// permutation. Error <= ~1.5e-3 absolute (f16 quantization), covered by MARGIN.
__global__ __launch_bounds__(256) void k_simh(const _Float16* __restrict__ Tq,
                                              const _Float16* __restrict__ Tk,
                                              float* __restrict__ cmax){
  __shared__ __align__(16) _Float16 skT[40*512];   // [kg 0..7][ks 0..4][cg][kk][8] = 40 KB
  __shared__ float smax[4][48];
  int tid = threadIdx.x;
  int wid = tid >> 6, lane = tid & 63;
  int wk = wid & 1, wq = wid >> 1;
  int q0 = blockIdx.x * 96;
  int cg = lane >> 4;
  int qb = q0 + wq*48 + (lane & 15);
  half8 fB[3][5];
  #pragma unroll
  for (int bf=0; bf<3; ++bf)
    #pragma unroll
    for (int ks=0; ks<5; ++ks)
      fB[bf][ks] = *(const half8*)(Tq + (size_t)(qb + bf*16)*CPAD + ks*32 + cg*8);
  int ch0 = blockIdx.y * NCHB;
  for (int cc=0; cc<NCHB; ++cc){
    int chunk = ch0 + cc;
    if (chunk >= NCHT) break;
    int kbase = chunk * KC;
    __syncthreads();            // prior chunk's skT reads & smax reads done
    #pragma unroll
    for (int it=0; it<10; ++it){
      int b1 = wid*10 + it;     // 1024-B block: kg=b1/5, ks=b1%5
      int kg = b1 / 5, ks = b1 % 5;
      const _Float16* g = Tk + (size_t)(kbase + kg*16 + (lane&15))*CPAD + ks*32 + cg*8;
      __builtin_amdgcn_global_load_lds((const __attribute__((address_space(1))) void*)g,
                                       (__attribute__((address_space(3))) void*)(skT + b1*512),
                                       16, 0, 0);
    }
    __syncthreads();            // staging complete (vmcnt drained before barrier)
    f32x4 acc[4][3];
    #pragma unroll
    for (int kf=0;kf<4;++kf)
      #pragma unroll
      for (int bf=0;bf<3;++bf)
        acc[kf][bf] = (f32x4){0.f,0.f,0.f,0.f};
    #pragma unroll
    for (int ks=0; ks<5; ++ks){
      #pragma unroll
      for (int kf=0; kf<4; ++kf){
        half8 av = *(const half8*)(skT + ((size_t)((wk*4+kf)*5 + ks))*512 + lane*8);
        #pragma unroll
        for (int bf=0; bf<3; ++bf)
          acc[kf][bf] = __builtin_amdgcn_mfma_f32_16x16x32_f16(av, fB[bf][ks], acc[kf][bf], 0, 0, 0);
      }
    }
    #pragma unroll
    for (int bf=0; bf<3; ++bf){
      float m = -1e30f;
      #pragma unroll
      for (int kf=0; kf<4; ++kf){
        f32x4 a = acc[kf][bf];
        m = fmaxf(m, fmaxf(fmaxf(a.x, a.y), fmaxf(a.z, a.w)));
      }
      m = fmaxf(m, __shfl_xor(m, 16));
      m = fmaxf(m, __shfl_xor(m, 32));
      if (lane < 16) smax[wid][bf*16 + lane] = m;
    }
    __syncthreads();
    if (tid < 96){
      int wqv = tid / 48, lc = tid - wqv*48;
      float vv = fmaxf(smax[2*wqv][lc], smax[2*wqv+1][lc]);
      cmax[(size_t)chunk*L + q0 + tid] = vv;
    }
  }
}

// ---------------- PASS 2: fp64 rescore of flagged chunks + final max/argmax
// one block per query. Flag: chunkmax >= gmax - MARGIN. Ascending chunk/key order;
// exact-tie -> min index (jnp.argmax first-occurrence semantics).
__global__ __launch_bounds__(256) void k_rescore(const float* __restrict__ Tq32,
                                                 const float* __restrict__ Tk32,
                                                 const float* __restrict__ cmax,
                                                 float* __restrict__ out){
  int q = blockIdx.x, tid = threadIdx.x;
  __shared__ float sq[FDIM];
  __shared__ float scm[NCHT];
  __shared__ float sgm;
  __shared__ double rv[256];
  __shared__ int   ri[256];
  if (tid < FDIM) sq[tid] = Tq32[(size_t)q*CPAD + tid];
  for (int g=tid; g<NCHT; g+=256) scm[g] = cmax[(size_t)g*L + q];
  __syncthreads();
  if (tid == 0){
    float gm = -1e30f;
    for (int c=0;c<NCHT;++c) gm = fmaxf(gm, scm[c]);
    sgm = gm;
  }
  __syncthreads();
  float thr = sgm - MARGIN;
  double best = -1e300; int bi = 0x7fffffff;
  for (int g=0; g<NCHT; ++g){
    if (scm[g] < thr) continue;
    int key = g*KC + tid;
    if (tid < KC && key < L){
      const float* kr = Tk32 + (size_t)key*CPAD;
      double a0=0.0, a1=0.0, a2=0.0, a3=0.0;
      for (int c=0;c<FDIM;c+=4){
        a0 += (double)sq[c+0]*(double)kr[c+0];
        a1 += (double)sq[c+1]*(double)kr[c+1];
        a2 += (double)sq[c+2]*(double)kr[c+2];
        a3 += (double)sq[c+3]*(double)kr[c+3];
      }
      double a = (a0+a1)+(a2+a3);
      if (a > best){ best = a; bi = key; }   // ascending keys -> first occurrence
    }
  }
  rv[tid] = best; ri[tid] = bi;
  __syncthreads();
  for (int s=128; s>0; s>>=1){
    if (tid < s){
      double v2 = rv[tid+s]; int i2 = ri[tid+s];
      if (v2 > rv[tid] || (v2 == rv[tid] && i2 < ri[tid])){ rv[tid] = v2; ri[tid] = i2; }
    }
    __syncthreads();
  }
  if (tid == 0){
    out[q]     = (float)rv[0];     // rel
    out[L + q] = (float)ri[0];     // idx (exact in f32: < 2^24)
  }
}

extern "C" void kernel_launch(void* const* d_in, const int* in_sizes, int n_in,
                              void* d_out, int out_size, void* d_ws, size_t ws_size,
                              hipStream_t stream){
  const float* query = (const float*)d_in[0];
  const float* key   = (const float*)d_in[1];
  const float* w1 = (const float*)d_in[2];
  const float* b1 = (const float*)d_in[3];
  const float* w2 = (const float*)d_in[4];
  const float* b2 = (const float*)d_in[5];
  const float* w3 = (const float*)d_in[6];
  const float* b3 = (const float*)d_in[7];
  const float* wm = (const float*)d_in[8];
  const float* bm = (const float*)d_in[9];
  float* out = (float*)d_out;

  // ---- workspace layout ----
  double* wd = (double*)d_ws;   // 114640 doubles of converted weights
  double* wd1 = wd;            // 1728
  double* bd1 = wd + 1728;     // 64
  double* wd2 = wd + 1792;     // 36864
  double* bd2 = wd + 38656;    // 64
  double* wd3 = wd + 38720;    // 73728
  double* bd3 = wd + 112448;   // 128
  double* wdm = wd + 112576;   // 2048
  double* bdm = wd + 114624;   // 16
  float* fbase = (float*)d_ws + 230400;
  float* nq = fbase;                            //   86400
  float* up = nq + 86400;                       //  345600
  float* A  = up + 345600;                      // 7372800  (conv1 out)
  float* Bf = A  + 7372800;                     // 7372800  (conv2 out)
  float* C  = A;                                // 1843200  (pool out; A dead after conv2)
  float* D  = A + 1843200;                      // 3686400  (conv3 out)
  float* FM = Bf + 7372800 - 460800;            //  460800  (1x1 out; Bf tail, Bf dead after pool)
  // pixel-major sim operands overlay A/Bf-head (all dead by k_patches time):
  _Float16* Tq16 = (_Float16*)A;                          // 14400*160 f16 = 1,152,000 fl
  _Float16* Tk16 = (_Float16*)(A + 1152000);              // 14464*160 f16 = 1,157,120 fl
  float*    Tq32 = A + 1152000 + 1157120;                 // 14400*160 f32 = 2,304,000 fl
  float*    Tk32 = Tq32 + 2304000;                        // 14464*160 f32 = 2,314,240 fl
  float*    cmax = Tk32 + 2314240;                        // 113*14400    = 1,627,200 fl
  // (ends at A+8,554,560 — inside A+Bf-head, clear of FM at Bf tail)

  k_cvt_all<<<(114640+255)/256, 256, 0, stream>>>(w1,b1,w2,b2,w3,b3,wm,bm, wd);

  k_prep   <<<(2*3*L + 255)/256, 256, 0, stream>>>(query, key, nq);
  k_bicubic<<<(2*3*H1*W1 + 255)/256, 256, 0, stream>>>(nq, up);
  k_conv3x3<3,3,240><<<dim3(64,8,2), 256, 0, stream>>>(up, wd1, bd1, A, 64);
  k_conv3x3<64,4,240><<<dim3(64,8,2), 256, 0, stream>>>(A, wd2, bd2, Bf, 64);
  k_maxpool<<<(2*64*L + 255)/256, 256, 0, stream>>>(Bf, C);
  k_conv3x3<64,4,120><<<dim3(16,16,2), 256, 0, stream>>>(C, wd3, bd3, D, 128);
  k_conv1x1<<<(2*L + 255)/256, 256, 0, stream>>>(D, wdm, bdm, FM);
  k_patches<<<(2*L + (LPAD-L) + 255)/256, 256, 0, stream>>>(FM, Tq16, Tk16, Tq32, Tk32);
  k_simh   <<<dim3(150, 15), 256, 0, stream>>>(Tq16, Tk16, cmax);
  k_rescore<<<L, 256, 0, stream>>>(Tq32, Tk32, cmax, out);
}